// Round 18
// baseline (219.881 us; speedup 1.0000x reference)
//
#include <hip/hip_runtime.h>
#include <math.h>

// Problem constants
constexpr int Dm  = 1024;
constexpr int Hh  = 16;
constexpr int HDm = 64;
constexpr int FFm = 4096;
constexpr int Bb  = 2;
constexpr int Sq  = 2048;
constexpr int Mm  = Bb * Sq;   // 4096 rows

typedef __attribute__((ext_vector_type(8))) short short8;
typedef __attribute__((ext_vector_type(4))) short short4v;
typedef __attribute__((ext_vector_type(4))) float f32x4;

#define AS1 __attribute__((address_space(1)))
#define AS3 __attribute__((address_space(3)))

// log2(e)/64 : folded into Q so scores come out of QK^T ready for exp2
constexpr float QSCALE = 0.022542110013890054f;

__device__ __forceinline__ unsigned short f2b(float f) {
    union { float f; unsigned u; } v; v.f = f;
    unsigned r = v.u + 0x7FFFu + ((v.u >> 16) & 1u);   // RNE
    return (unsigned short)(r >> 16);
}
__device__ __forceinline__ float b2f(unsigned short s) {
    union { unsigned u; float f; } v; v.u = ((unsigned)s) << 16;
    return v.f;
}

// tanh-form GELU in exp2 domain: x * sigmoid(x*(c1 + c2*x^2)), overflow-safe.
__device__ __forceinline__ float gelu_fast(float x) {
    float z = x * (2.302080918f + 0.102938049f * x * x);
    return x * __builtin_amdgcn_rcpf(1.0f + exp2f(-z));
}

// ---------------------------------------------------------------------------
// Fused prep kernel: one launch does everything.
// ---------------------------------------------------------------------------
__device__ __forceinline__ void transpose_body(
    const float* __restrict__ src, short* __restrict__ dst,
    int R, int C, int bx, int by, int tid, float (*t)[65])
{
    const int c0 = bx * 64, r0 = by * 64;
    const int lc = tid & 63, lr4 = tid >> 6;
    #pragma unroll
    for (int p = 0; p < 16; ++p) {
        int rr = p * 4 + lr4;
        t[rr][lc] = src[(size_t)(r0 + rr) * C + c0 + lc];
    }
    __syncthreads();
    #pragma unroll
    for (int p = 0; p < 16; ++p) {
        int rr = p * 4 + lr4;
        dst[(size_t)(c0 + rr) * R + r0 + lc] = (short)f2b(t[lc][rr]);
    }
}

__global__ __launch_bounds__(256) void prep_all(
    const float* __restrict__ x,  short* __restrict__ xb,
    const float* __restrict__ Wq, const float* __restrict__ Wk,
    const float* __restrict__ Wv, short* __restrict__ wqkvt,
    const float* __restrict__ bq, const float* __restrict__ bk,
    const float* __restrict__ bv, float* __restrict__ bcat,
    const float* __restrict__ Wo, short* __restrict__ wot,
    const float* __restrict__ W1, short* __restrict__ w1t,
    const float* __restrict__ W2, short* __restrict__ w2t)
{
    __shared__ float t[64][65];
    const int bid = blockIdx.x, tid = threadIdx.x;
    if (bid < 256) {
        transpose_body(Wo, wot, Dm, Dm, bid & 15, bid >> 4, tid, t);
    } else if (bid < 1280) {
        int lo = bid - 256;
        transpose_body(W1, w1t, Dm, FFm, lo & 63, lo >> 6, tid, t);
    } else if (bid < 2304) {
        int lo = bid - 1280;
        transpose_body(W2, w2t, FFm, Dm, lo & 15, lo >> 4, tid, t);
    } else if (bid < 2316) {
        int n = (bid - 2304) * 256 + tid;
        const float* s = (n < 1024) ? bq : (n < 2048) ? bk : bv;
        bcat[n] = s[n & 1023];
    } else if (bid < 3084) {
        int lo = bid - 2316;
        const int kt = lo & 15, h = (lo >> 4) & 15, which = lo >> 8;
        const float* W = ((which == 0) ? Wq : (which == 1) ? Wk : Wv) +
                         (size_t)h * Dm * HDm;
        const int lc = tid & 63, lr4 = tid >> 6;
        #pragma unroll
        for (int p = 0; p < 16; ++p) {
            int kr = p * 4 + lr4;
            t[kr][lc] = W[(size_t)(kt * 64 + kr) * HDm + lc];
        }
        __syncthreads();
        const int nbase = which * 1024 + h * 64;
        #pragma unroll
        for (int p = 0; p < 16; ++p) {
            int e = p * 4 + lr4;
            wqkvt[(size_t)(nbase + e) * Dm + kt * 64 + lc] = (short)f2b(t[lc][e]);
        }
    } else {
        int i = (bid - 3084) * 256 + tid;            // float4 index
        float4 v = ((const float4*)x)[i];
        short4v o;
        o[0] = (short)f2b(v.x); o[1] = (short)f2b(v.y);
        o[2] = (short)f2b(v.z); o[3] = (short)f2b(v.w);
        ((short4v*)xb)[i] = o;
    }
}

// ---------------------------------------------------------------------------
// 8-phase 256x256 MFMA GEMM: QKV only (EPI 2). 512 thr = 8 waves,
// BK=64, 128 KiB LDS dbuf, counted vmcnt, swapped mfma(bf,af), T1 remap.
// ---------------------------------------------------------------------------
template<int EPI>
__global__ __launch_bounds__(512, 2) void gemm256(
    const short* __restrict__ A, const short* __restrict__ Bt,
    const float* __restrict__ bias,
    short* __restrict__ outb,
    short* __restrict__ qo, short* __restrict__ ko, short* __restrict__ vo,
    int K, int N, int NMT)
{
    __shared__ __align__(16) char lds[131072];
    char* const ldsA = lds;              // [buf][half] 16KB each
    char* const ldsB = lds + 65536;
    const int tid = threadIdx.x;
    const int l = tid & 63, wv = tid >> 6;
    const int wm = wv >> 2, wn = wv & 3;
    const int lr = l & 15, lg = l >> 4;
    const int cpx = gridDim.x >> 3;
    const int bid = (blockIdx.x & 7) * cpx + (blockIdx.x >> 3);
    const int m0 = (bid % NMT) * 256;
    const int n0 = (bid / NMT) * 256;
    const size_t KB = (size_t)K * 2;
    const int NT = K >> 6;

    const char* pA[2][2];
    const char* pB[2][2];
    #pragma unroll
    for (int i = 0; i < 2; ++i) {
        int c = tid + 512 * i;
        int rh = c >> 3, j = c & 7;
        int sw = (j ^ (rh & 7)) << 4;
        #pragma unroll
        for (int h = 0; h < 2; ++h) {
            pA[h][i] = (const char*)A + (size_t)(m0 + h * 128 + rh) * KB + sw;
            pB[h][i] = (const char*)Bt + (size_t)(n0 + h * 128 + rh) * KB + sw;
        }
    }
    const int dbase = tid * 16;

    f32x4 acc[8][4];
    f32x4 z4 = {0.f, 0.f, 0.f, 0.f};
    #pragma unroll
    for (int i = 0; i < 8; ++i)
        #pragma unroll
        for (int j = 0; j < 4; ++j) acc[i][j] = z4;

#define STAGE_B(h, nb) do {                                                     \
    char* _b = ldsB + ((nb) * 2 + (h)) * 16384;                                 \
    __builtin_amdgcn_global_load_lds((const AS1 void*)pB[h][0],                 \
        (AS3 void*)(_b + dbase), 16, 0, 0);                                     \
    __builtin_amdgcn_global_load_lds((const AS1 void*)pB[h][1],                 \
        (AS3 void*)(_b + dbase + 8192), 16, 0, 0);                              \
    pB[h][0] += 128; pB[h][1] += 128; } while (0)
#define STAGE_A(h, nb) do {                                                     \
    char* _a = ldsA + ((nb) * 2 + (h)) * 16384;                                 \
    __builtin_amdgcn_global_load_lds((const AS1 void*)pA[h][0],                 \
        (AS3 void*)(_a + dbase), 16, 0, 0);                                     \
    __builtin_amdgcn_global_load_lds((const AS1 void*)pA[h][1],                 \
        (AS3 void*)(_a + dbase + 8192), 16, 0, 0);                              \
    pA[h][0] += 128; pA[h][1] += 128; } while (0)

    STAGE_B(0, 0); STAGE_B(1, 0); STAGE_A(0, 0); STAGE_A(1, 0);
    asm volatile("s_waitcnt vmcnt(2)" ::: "memory");
    __builtin_amdgcn_s_barrier();
    __builtin_amdgcn_sched_barrier(0);

    const int swk0 = ((0 + lg) ^ (lr & 7)) << 4;
    const int swk1 = ((4 + lg) ^ (lr & 7)) << 4;

    for (int kt = 0; kt < NT; ++kt) {
        const int buf = kt & 1, nbuf = buf ^ 1;
        const bool more = (kt + 1 < NT);
        char* const Ah0 = ldsA + (buf * 2) * 16384;
        char* const Ah1 = ldsA + (buf * 2 + 1) * 16384;
        char* const Bh  = ldsB + (buf * 2 + (wn >> 1)) * 16384 + (wn & 1) * 8192;

        short8 bf[4][2];
        #pragma unroll
        for (int nf = 0; nf < 4; ++nf) {
            const char* bb = Bh + (nf * 16 + lr) * 128;
            bf[nf][0] = *(const short8*)(bb + swk0);
            bf[nf][1] = *(const short8*)(bb + swk1);
        }
        short8 af[2][2];

#define LOAD_A(p) do {                                                          \
    _Pragma("unroll")                                                           \
    for (int j2 = 0; j2 < 2; ++j2) {                                            \
        const int mf = 2 * (p) + j2;                                            \
        const char* ab = ((mf >> 2) ? Ah1 : Ah0) +                              \
                         ((mf & 3) * 32 + wm * 16 + lr) * 128;                  \
        af[j2][0] = *(const short8*)(ab + swk0);                                \
        af[j2][1] = *(const short8*)(ab + swk1);                                \
    } } while (0)

#define MFMA8(p) do {                                                           \
    _Pragma("unroll")                                                           \
    for (int j2 = 0; j2 < 2; ++j2)                                              \
        _Pragma("unroll")                                                       \
        for (int nf = 0; nf < 4; ++nf) {                                        \
            acc[2 * (p) + j2][nf] = __builtin_amdgcn_mfma_f32_16x16x32_bf16(    \
                bf[nf][0], af[j2][0], acc[2 * (p) + j2][nf], 0, 0, 0);          \
            acc[2 * (p) + j2][nf] = __builtin_amdgcn_mfma_f32_16x16x32_bf16(    \
                bf[nf][1], af[j2][1], acc[2 * (p) + j2][nf], 0, 0, 0);          \
        } } while (0)

        // ---- phase 0 ----
        LOAD_A(0);
        if (more) STAGE_B(0, nbuf);
        __builtin_amdgcn_s_barrier();
        asm volatile("s_waitcnt lgkmcnt(0)" ::: "memory");
        __builtin_amdgcn_sched_barrier(0);
        __builtin_amdgcn_s_setprio(1);
        MFMA8(0);
        __builtin_amdgcn_s_setprio(0);
        __builtin_amdgcn_s_barrier();
        // ---- phase 1 ----
        LOAD_A(1);
        if (more) STAGE_B(1, nbuf);
        __builtin_amdgcn_s_barrier();
        asm volatile("s_waitcnt lgkmcnt(0)" ::: "memory");
        __builtin_amdgcn_sched_barrier(0);
        __builtin_amdgcn_s_setprio(1);
        MFMA8(1);
        __builtin_amdgcn_s_setprio(0);
        if (more) asm volatile("s_waitcnt vmcnt(4)" ::: "memory");
        else      asm volatile("s_waitcnt vmcnt(0)" ::: "memory");
        __builtin_amdgcn_s_barrier();
        __builtin_amdgcn_sched_barrier(0);
        // ---- phase 2 ----
        LOAD_A(2);
        if (more) STAGE_A(0, nbuf);
        __builtin_amdgcn_s_barrier();
        asm volatile("s_waitcnt lgkmcnt(0)" ::: "memory");
        __builtin_amdgcn_sched_barrier(0);
        __builtin_amdgcn_s_setprio(1);
        MFMA8(2);
        __builtin_amdgcn_s_setprio(0);
        __builtin_amdgcn_s_barrier();
        // ---- phase 3 ----
        LOAD_A(3);
        if (more) STAGE_A(1, nbuf);
        __builtin_amdgcn_s_barrier();
        asm volatile("s_waitcnt lgkmcnt(0)" ::: "memory");
        __builtin_amdgcn_sched_barrier(0);
        __builtin_amdgcn_s_setprio(1);
        MFMA8(3);
        __builtin_amdgcn_s_setprio(0);
        asm volatile("s_waitcnt vmcnt(2)" ::: "memory");
        __builtin_amdgcn_s_barrier();
        __builtin_amdgcn_sched_barrier(0);
#undef LOAD_A
#undef MFMA8
    }

    // epilogue (swapped C layout): per (mf,nf): m = ..+lr, n = nb + r
    #pragma unroll
    for (int mf = 0; mf < 8; ++mf) {
        #pragma unroll
        for (int nf = 0; nf < 4; ++nf) {
            const int m  = m0 + mf * 32 + wm * 16 + lr;
            const int nb = n0 + wn * 64 + nf * 16 + lg * 4;
            const float4 b4 = *(const float4*)&bias[nb];
            float v0 = acc[mf][nf][0] + b4.x;
            float v1 = acc[mf][nf][1] + b4.y;
            float v2 = acc[mf][nf][2] + b4.z;
            float v3 = acc[mf][nf][3] + b4.w;
            if (EPI == 1) {
                short4v pk;
                pk[0] = (short)f2b(gelu_fast(v0));
                pk[1] = (short)f2b(gelu_fast(v1));
                pk[2] = (short)f2b(gelu_fast(v2));
                pk[3] = (short)f2b(gelu_fast(v3));
                *(short4v*)&outb[(size_t)m * N + nb] = pk;
            } else {
                const int which = nb >> 10, hh = (nb >> 6) & 15, e0 = nb & 63;
                const int bb2 = m >> 11, ss = m & 2047;
                if (which == 2) {
                    size_t base = (((size_t)bb2 * Hh + hh) * HDm + e0) * Sq + ss;
                    vo[base]          = (short)f2b(v0);
                    vo[base + Sq]     = (short)f2b(v1);
                    vo[base + 2 * Sq] = (short)f2b(v2);
                    vo[base + 3 * Sq] = (short)f2b(v3);
                } else {
                    short* o = (which == 0) ? qo : ko;
                    const float sc = (which == 0) ? QSCALE : 1.0f;
                    short4v pk;
                    pk[0] = (short)f2b(v0 * sc);
                    pk[1] = (short)f2b(v1 * sc);
                    pk[2] = (short)f2b(v2 * sc);
                    pk[3] = (short)f2b(v3 * sc);
                    *(short4v*)&o[(((size_t)bb2 * Hh + hh) * Sq + ss) * HDm + e0] = pk;
                }
            }
        }
    }
#undef STAGE_A
#undef STAGE_B
}

// ---------------------------------------------------------------------------
// Deep-pipelined BMx128 GEMM (T3+T4), 2-phase, swapped mfma, R16 ledger.
// EPI 1: outb = bf16(gelu(acc+bias))          (FF1)
// EPI 2: outf = acc + bias + res_bf16 (f32)   (Wo, FF2)
// ---------------------------------------------------------------------------
template<int EPI, int BM>
__global__ __launch_bounds__(256, 2) void gemm128dp(
    const short* __restrict__ A, const short* __restrict__ Bt,
    const float* __restrict__ bias,
    const short* __restrict__ resb,
    float* __restrict__ outf, short* __restrict__ outb,
    int K, int N)
{
    constexpr int AR  = BM / 32;
    constexpr int BMW = BM / 2;
    constexpr int MF  = BMW / 16;
    constexpr int ABUF = BM * 128;
    __shared__ __align__(16) char lds[2 * ABUF + 32768];
    char* const ldsA = lds;
    char* const ldsB = lds + 2 * ABUF;
    const int tid = threadIdx.x;
    const int l = tid & 63, wv = tid >> 6;
    const int wr = wv >> 1, wc = wv & 1;
    const int lr = l & 15, lg = l >> 4;
    const int m0 = blockIdx.x * BM, n0 = blockIdx.y * 128;
    const size_t KB = (size_t)K * 2;
    const int NT = K >> 6;

    const int r0 = tid >> 3, jj = tid & 7;
    const int sw = (jj ^ (r0 & 7)) << 4;
    const char* aSrc[AR]; const char* bSrc1[2]; const char* bSrc2[2];
    #pragma unroll
    for (int i = 0; i < AR; ++i)
        aSrc[i] = (const char*)A + (size_t)(m0 + r0 + 32 * i) * KB + sw;
    #pragma unroll
    for (int i = 0; i < 2; ++i) {
        bSrc1[i] = (const char*)Bt + (size_t)(n0 + r0 + 64 * i) * KB + sw;
        bSrc2[i] = (const char*)Bt + (size_t)(n0 + 32 + r0 + 64 * i) * KB + sw;
    }
    const int aDst0 = tid * 16;

#define STAGE_SA(nb) do {                                                       \
    char* _a = ldsA + (nb) * ABUF;                                              \
    _Pragma("unroll")                                                           \
    for (int i = 0; i < AR; ++i) {                                              \
        __builtin_amdgcn_global_load_lds((const AS1 void*)aSrc[i],              \
            (AS3 void*)(_a + aDst0 + i * 4096), 16, 0, 0);                      \
        aSrc[i] += 128;                                                         \
    } } while (0)
#define STAGE_SB1(nb) do {                                                      \
    char* _b = ldsB + (nb) * 16384;                                             \
    _Pragma("unroll")                                                           \
    for (int i = 0; i < 2; ++i) {                                               \
        __builtin_amdgcn_global_load_lds((const AS1 void*)bSrc1[i],             \
            (AS3 void*)(_b + aDst0 + i * 8192), 16, 0, 0);                      \
        bSrc1[i] += 128;                                                        \
    } } while (0)
#define STAGE_SB2(nb) do {                                                      \
    char* _b = ldsB + (nb) * 16384 + 4096;                                      \
    _Pragma("unroll")                                                           \
    for (int i = 0; i < 2; ++i) {                                               \
        __builtin_amdgcn_global_load_lds((const AS1 void*)bSrc2[i],             \
            (AS3 void*)(_b + aDst0 + i * 8192), 16, 0, 0);                      \
        bSrc2[i] += 128;                                                        \
    } } while (0)

    f32x4 acc[MF][4];
    f32x4 z4 = {0.f, 0.f, 0.f, 0.f};
    #pragma unroll
    for (int i = 0; i < MF; ++i)
        #pragma unroll
        for (int j = 0; j < 4; ++j) acc[i][j] = z4;

    STAGE_SA(0); STAGE_SB1(0); STAGE_SB2(0);
    asm volatile("s_waitcnt vmcnt(2)" ::: "memory");
    __builtin_amdgcn_s_barrier();
    __builtin_amdgcn_sched_barrier(0);

    for (int kt = 0; kt < NT; ++kt) {
        const int buf = kt & 1, nbuf = buf ^ 1;
        const bool more = (kt + 1 < NT);
        char* const Ab = ldsA + buf * ABUF;
        char* const Bb = ldsB + buf * 16384;

        // ---- phase 1: nf {0,1}; stage ALL of tile t+1 ----
        short8 af[MF][2], bf[2][2];
        #pragma unroll
        for (int mf = 0; mf < MF; ++mf) {
            const int row = wr * BMW + mf * 16 + lr;
            const char* ab = Ab + row * 128;
            af[mf][0] = *(const short8*)(ab + (((0 + lg) ^ (row & 7)) << 4));
            af[mf][1] = *(const short8*)(ab + (((4 + lg) ^ (row & 7)) << 4));
        }
        #pragma unroll
        for (int nf = 0; nf < 2; ++nf) {
            const int row = wc * 64 + nf * 16 + lr;
            const char* bb = Bb + row * 128;
            bf[nf][0] = *(const short8*)(bb + (((0 + lg) ^ (row & 7)) << 4));
            bf[nf][1] = *(const short8*)(bb + (((4 + lg) ^ (row & 7)) << 4));
        }
        if (more) { STAGE_SA(nbuf); STAGE_SB1(nbuf); STAGE_SB2(nbuf); }
        asm volatile("s_waitcnt lgkmcnt(0)" ::: "memory");
        __builtin_amdgcn_sched_barrier(0);
        __builtin_amdgcn_s_setprio(1);
        #pragma unroll
        for (int mf = 0; mf < MF; ++mf)
            #pragma unroll
            for (int nf = 0; nf < 2; ++nf) {
                acc[mf][nf] = __builtin_amdgcn_mfma_f32_16x16x32_bf16(
                    bf[nf][0], af[mf][0], acc[mf][nf], 0, 0, 0);
                acc[mf][nf] = __builtin_amdgcn_mfma_f32_16x16x32_bf16(
                    bf[nf][1], af[mf][1], acc[mf][nf], 0, 0, 0);
            }
        __builtin_amdgcn_s_setprio(0);
        if (more) asm volatile("s_waitcnt vmcnt(6)" ::: "memory");   // forces SB2(t)
        else      asm volatile("s_waitcnt vmcnt(0)" ::: "memory");
        __builtin_amdgcn_s_barrier();
        __builtin_amdgcn_sched_barrier(0);

        // ---- phase 2: nf {2,3} ----
        #pragma unroll
        for (int nf = 0; nf < 2; ++nf) {
            const int row = wc * 64 + (nf + 2) * 16 + lr;
            const char* bb = Bb + row * 128;
            bf[nf][0] = *(const short8*)(bb + (((0 + lg) ^ (row & 7)) << 4));
            bf[nf][1] = *(const short8*)(bb + (((4 + lg) ^ (row & 7)) << 4));
        }
        asm volatile("s_waitcnt lgkmcnt(0)" ::: "memory");
        __builtin_amdgcn_sched_barrier(0);
        __builtin_amdgcn_s_setprio(1);
        #pragma unroll
        for (int mf = 0; mf < MF; ++mf)
            #pragma unroll
            for (int nf = 0; nf < 2; ++nf) {
                acc[mf][nf + 2] = __builtin_amdgcn_mfma_f32_16x16x32_bf16(
                    bf[nf][0], af[mf][0], acc[mf][nf + 2], 0, 0, 0);
                acc[mf][nf + 2] = __builtin_amdgcn_mfma_f32_16x16x32_bf16(
                    bf[nf][1], af[mf][1], acc[mf][nf + 2], 0, 0, 0);
            }
        __builtin_amdgcn_s_setprio(0);
        if (more) {
            asm volatile("s_waitcnt vmcnt(2)" ::: "memory");   // forces SA,SB1(t+1)
            __builtin_amdgcn_s_barrier();
            __builtin_amdgcn_sched_barrier(0);
        }
    }

    // epilogue (swapped C layout)
    #pragma unroll
    for (int mf = 0; mf < MF; ++mf) {
        #pragma unroll
        for (int nf = 0; nf < 4; ++nf) {
            const int m  = m0 + wr * BMW + mf * 16 + lr;
            const int nb = n0 + wc * 64 + nf * 16 + lg * 4;
            const float4 b4 = *(const float4*)&bias[nb];
            float v0 = acc[mf][nf][0] + b4.x;
            float v1 = acc[mf][nf][1] + b4.y;
            float v2 = acc[mf][nf][2] + b4.z;
            float v3 = acc[mf][nf][3] + b4.w;
            if (EPI == 1) {
                short4v pk;
                pk[0] = (short)f2b(gelu_fast(v0));
                pk[1] = (short)f2b(gelu_fast(v1));
                pk[2] = (short)f2b(gelu_fast(v2));
                pk[3] = (short)f2b(gelu_fast(v3));
                *(short4v*)&outb[(size_t)m * N + nb] = pk;
            } else {
                const short4v r4 = *(const short4v*)&resb[(size_t)m * N + nb];
                float4 o4;
                o4.x = v0 + b2f((unsigned short)r4[0]);
                o4.y = v1 + b2f((unsigned short)r4[1]);
                o4.z = v2 + b2f((unsigned short)r4[2]);
                o4.w = v3 + b2f((unsigned short)r4[3]);
                *(float4*)&outf[(size_t)m * N + nb] = o4;
            }
        }
    }
#undef STAGE_SA
#undef STAGE_SB1
#undef STAGE_SB2
}

// ---------------------------------------------------------------------------
// MFMA flash attention v10 (R15/R17): QBLK=64, 4 waves, KVBLK=128.
// ---------------------------------------------------------------------------
__global__ __launch_bounds__(256) void attn_mfma(
    const short* __restrict__ qg, const short* __restrict__ kg,
    const short* __restrict__ vtg, short* __restrict__ ctx)
{
    const int bid = blockIdx.x;
    const int qt = (Sq / 64 - 1) - (bid >> 5);    // heavy blocks first
    const int hb = bid & 31;
    const int h = hb & 15, b = hb >> 4;
    const int tid = threadIdx.x;
    const int l = tid & 63, wv = tid >> 6;
    const int lr = l & 15, lg = l >> 4;

    __shared__ __align__(16) char KlB[16384];     // 128 key-rows x 128B, swz
    __shared__ __align__(16) char VtB[16384];     // 64 d-rows x 256B, swz
    __shared__ __align__(16) char PlB[4][4096];   // per wave 16 rows x 256B, swz

    const size_t bh = ((size_t)b * Hh + h) * Sq;
    const size_t vbase = ((size_t)b * Hh + h) * HDm * Sq;

    const int qbase = qt * 64 + wv * 16;
    short8 aq[2];
    #pragma unroll
    for (int ks = 0; ks < 2; ++ks)
        aq[ks] = *(const short8*)(qg + (bh + qbase + lr) * HDm + ks * 32 + lg * 8);

    f32x4 zero4 = {0.f, 0.f, 0.f, 0.f};
    f32x4 oacc[4], lacc = zero4;
    #pragma unroll
    for (int i = 0; i < 4; ++i) oacc[i] = zero4;
    float mreg[4];
    #pragma unroll
    for (int r = 0; r < 4; ++r) mreg[r] = -3e38f;

    short8 vone;
    #pragma unroll
    for (int j = 0; j < 8; ++j) vone[j] = (short)0x3F80;   // bf16 1.0

    char* plw = PlB[wv];

    const char* srcK[4]; const char* srcV[4];
    #pragma unroll
    for (int i = 0; i < 4; ++i) {
        int c = tid + 256 * i;
        int rowK = c >> 3, jK = c & 7;              // K: 128 rows x 8 chunks
        srcK[i] = (const char*)kg + ((bh + rowK) * HDm + ((jK ^ (rowK & 7)) * 8)) * 2;
        int rowV = c >> 4, jV = c & 15;             // Vt: 64 rows x 16 chunks
        srcV[i] = (const char*)vtg + (vbase + (size_t)rowV * Sq + ((jV ^ (rowV & 7)) * 8)) * 2;
    }

    const int nt = (qt + 2) >> 1;                   // ceil((qt+1)/2)
    for (int tk = 0; tk < nt; ++tk) {
        __syncthreads();
        #pragma unroll
        for (int i = 0; i < 4; ++i) {
            int c = tid + 256 * i;
            __builtin_amdgcn_global_load_lds((const AS1 void*)srcK[i],
                (AS3 void*)(KlB + c * 16), 16, 0, 0);
            srcK[i] += 128 * HDm * 2;               // next 128-key tile
            __builtin_amdgcn_global_load_lds((const AS1 void*)srcV[i],
                (AS3 void*)(VtB + c * 16), 16, 0, 0);
            srcV[i] += 128 * 2;                     // 128 keys along S
        }
        __syncthreads();

        // QK^T: S[16 q][128 key]
        f32x4 sc[8];
        #pragma unroll
        for (int i = 0; i < 8; ++i) sc[i] = zero4;
        __builtin_amdgcn_s_setprio(1);
        #pragma unroll
        for (int kd = 0; kd < 2; ++kd) {
            #pragma unroll
            for (int nf = 0; nf < 8; ++nf) {
                short8 bk = *(const short8*)(KlB + (nf * 16 + lr) * 128 +
                                (((kd * 4 + lg) ^ (lr & 7)) << 4));
                sc[nf] = __builtin_amdgcn_mfma_f32_16x16x32_bf16(
                    aq[kd], bk, sc[nf], 0, 0, 0);
            }
        }
        __builtin_amdgcn_s_setprio(0);

        // mask (last tile only)
        if (tk == nt - 1) {
            #pragma unroll
            for (int r = 0; r < 4; ++r) {
                const int qglob = qbase + lg * 4 + r;
                #pragma unroll
                for (int nf = 0; nf < 8; ++nf)
                    if (tk * 128 + nf * 16 + lr > qglob) sc[nf][r] = -3e38f;
            }
        }

        // fast-path softmax: per-lane max (serial chain -> v_max3 fusion)
        float lm[4];
        #pragma unroll
        for (int r = 0; r < 4; ++r) {
            float m01 = fmaxf(fmaxf(fmaxf(sc[0][r], sc[1][r]), sc[2][r]), sc[3][r]);
            lm[r] = fmaxf(fmaxf(fmaxf(fmaxf(m01, sc[4][r]), sc[5][r]), sc[6][r]), sc[7][r]);
        }
        bool grow = (lm[0] > mreg[0] + 8.f) || (lm[1] > mreg[1] + 8.f) ||
                    (lm[2] > mreg[2] + 8.f) || (lm[3] > mreg[3] + 8.f);

        if (__any((int)grow)) {
            #pragma unroll
            for (int r = 0; r < 4; ++r) {
                float mr = lm[r];
                #pragma unroll
                for (int o = 1; o < 16; o <<= 1)
                    mr = fmaxf(mr, __shfl_xor(mr, o));
                float mnew = fmaxf(mreg[r], mr);
                float cf = exp2f(mreg[r] - mnew);
                mreg[r] = mnew;
                const int prow = lg * 4 + r;
                #pragma unroll
                for (int nf = 0; nf < 8; ++nf) {
                    float p = exp2f(sc[nf][r] - mnew);
                    *(unsigned short*)(plw + prow * 256 +
                        (((nf * 2 + (lr >> 3)) ^ (prow & 7)) << 4) +
                        ((lr & 7) << 1)) = (unsigned short)(__float_as_uint(p) >> 16);
                }
                #pragma unroll
                for (int nf = 0; nf < 4; ++nf) oacc[nf][r] *= cf;
                lacc[r] *= cf;
            }
        } else {
            #pragma unroll
            for (int r = 0; r < 4; ++r) {
                const int prow = lg * 4 + r;
                #pragma unroll
                for (int nf = 0; nf < 8; ++nf) {
                    float p = exp2f(sc[nf][r] - mreg[r]);
                    *(unsigned short*)(plw + prow * 256 +
                        (((nf * 2 + (lr >> 3)) ^ (prow & 7)) << 4) +
                        ((lr & 7) << 1)) = (unsigned short)(__float_as_uint(p) >> 16);
                }
            }
        }

        asm volatile("s_waitcnt lgkmcnt(0)" ::: "memory");
        __builtin_amdgcn_sched_barrier(0);

        // PV: O[16 q][64 d] += P @ V over 128 keys ; l via ones-MFMA
        __builtin_amdgcn_s_setprio(1);
        #pragma unroll
        for (int ks = 0; ks < 4; ++ks) {
            short8 pa = *(const short8*)(plw + lr * 256 +
                            (((ks * 4 + lg) ^ (lr & 7)) << 4));
            #pragma unroll
            for (int nf = 0; nf < 4; ++nf) {
                short8 bv8 = *(const short8*)(VtB + (nf * 16 + lr) * 256 +
                                (((ks * 4 + lg) ^ (lr & 7)) << 4));
                oacc[nf] = __builtin_amdgcn_mfma_f32_16x16x32_bf16(
                    pa, bv8, oacc[nf], 0, 0, 0);
            }
            lacc = __builtin_amdgcn_mfma_f32_16x16x32_bf16(pa, vone, lacc, 0, 0, 0);
        }
        __builtin_amdgcn_s_setprio(0);
    }

    #pragma unroll
    for (int r = 0; r < 4; ++r) {
        float inv = 1.0f / lacc[r];
        int q = qbase + lg * 4 + r;
        size_t o = ((size_t)b * Sq + q) * Dm + h * HDm;
        #pragma unroll
        for (int nf = 0; nf < 4; ++nf)
            ctx[o + nf * 16 + lr] = (short)f2b(oacc[nf][r] * inv);
    }
}

// ---------------------------------------------------------------------------
// Row LayerNorm: block per row (1024), 256 thr x float4.
// MODE 0: f32 out (final). MODE 1: bf16 out only (feeds FF1 + FF2 residual).
// ---------------------------------------------------------------------------
template<int MODE>
__global__ __launch_bounds__(256) void ln_kernel(
    const float* __restrict__ in, const float* __restrict__ g,
    const float* __restrict__ be, float* __restrict__ outf,
    short* __restrict__ outb)
{
    const int m = blockIdx.x;
    const int tid = threadIdx.x;
    const float4 vl = *(const float4*)&in[(size_t)m * Dm + tid * 4];
    float s  = vl.x + vl.y + vl.z + vl.w;
    float s2 = vl.x * vl.x + vl.y * vl.y + vl.z * vl.z + vl.w * vl.w;
    #pragma unroll
    for (int o = 32; o > 0; o >>= 1) {
        s  += __shfl_down(s, o);
        s2 += __shfl_down(s2, o);
    }
    __shared__ float rs[4], rs2[4];
    const int w = tid >> 6;
    if ((tid & 63) == 0) { rs[w] = s; rs2[w] = s2; }
    __syncthreads();
    s  = rs[0] + rs[1] + rs[2] + rs[3];
    s2 = rs2[0] + rs2[1] + rs2[2] + rs2[3];
    const float mean = s * (1.0f / Dm);
    const float var  = s2 * (1.0f / Dm) - mean * mean;
    const float rstd = rsqrtf(var + 1e-5f);
    const float4 gv = *(const float4*)&g[tid * 4];
    const float4 bv = *(const float4*)&be[tid * 4];
    float4 ov;
    ov.x = (vl.x - mean) * rstd * gv.x + bv.x;
    ov.y = (vl.y - mean) * rstd * gv.y + bv.y;
    ov.z = (vl.z - mean) * rstd * gv.z + bv.z;
    ov.w = (vl.w - mean) * rstd * gv.w + bv.w;
    if (MODE == 0) {
        *(float4*)&outf[(size_t)m * Dm + tid * 4] = ov;
    } else {
        short4v o4;
        o4[0] = (short)f2b(ov.x); o4[1] = (short)f2b(ov.y);
        o4[2] = (short)f2b(ov.z); o4[3] = (short)f2b(ov.w);
        *(short4v*)&outb[(size_t)m * Dm + tid * 4] = o4;
    }
}

// ---------------------------------------------------------------------------
extern "C" void kernel_launch(void* const* d_in, const int* in_sizes, int n_in,
                              void* d_out, int out_size, void* d_ws, size_t ws_size,
                              hipStream_t stream)
{
    const float* x  = (const float*)d_in[0];
    const float* Wq = (const float*)d_in[1];
    const float* bq = (const float*)d_in[2];
    const float* Wk = (const float*)d_in[3];
    const float* bk = (const float*)d_in[4];
    const float* Wv = (const float*)d_in[5];
    const float* bv = (const float*)d_in[6];
    const float* Wo = (const float*)d_in[7];
    const float* bo = (const float*)d_in[8];
    const float* W1 = (const float*)d_in[9];
    const float* b1 = (const float*)d_in[10];
    const float* W2 = (const float*)d_in[11];
    const float* b2 = (const float*)d_in[12];
    const float* g1 = (const float*)d_in[13];
    const float* be1= (const float*)d_in[14];
    const float* g2 = (const float*)d_in[15];
    const float* be2= (const float*)d_in[16];
    float* out = (float*)d_out;

    char* ws = (char*)d_ws;
    size_t off = 0;
    auto alloc = [&](size_t bytes) {
        char* p = ws + off;
        off += (bytes + 255) & ~(size_t)255;
        return p;
    };
    const size_t MD2 = (size_t)Mm * Dm * 2;          // 8 MB
    short* xb    = (short*)alloc(MD2);
    short* wqkvt = (short*)alloc((size_t)3072 * Dm * 2);
    float* bcat  = (float*)alloc(3072 * 4);
    short* wot   = (short*)alloc((size_t)Dm * Dm * 2);
    short* w1t   = (short*)alloc((size_t)FFm * Dm * 2);
    short* w2t   = (short*)alloc((size_t)Dm * FFm * 2);
    short* qb    = (short*)alloc(MD2);
    short* kb    = (short*)alloc(MD2);
    short* vtb   = (short*)alloc(MD2);               // V transposed [B,H,64,S]
    short* ctxb  = (short*)alloc(MD2);
    short* hb    = qb;                                // alias: q/k dead by FF1
    float* y     = (float*)alloc((size_t)Mm * Dm * 4);
    short* x1b   = (short*)alloc(MD2);
    float* y2    = y;                                 // alias: y dead after LN1

    // --- fused prep (1 launch) ---
    prep_all<<<7180, 256, 0, stream>>>(
        x, xb, Wq, Wk, Wv, wqkvt, bq, bk, bv, bcat,
        Wo, wot, W1, w1t, W2, w2t);

    // --- decoder layer ---
    gemm256<2><<<192, 512, 0, stream>>>(
        xb, wqkvt, bcat, nullptr, qb, kb, vtb, Dm, 3072, 16);
    attn_mfma<<<1024, 256, 0, stream>>>(qb, kb, vtb, ctxb);
    gemm128dp<2, 64><<<dim3(64, 8), 256, 0, stream>>>(
        ctxb, wot, bo, xb, y, nullptr, Dm, Dm);
    ln_kernel<1><<<Mm, 256, 0, stream>>>(y, g1, be1, nullptr, x1b);
    gemm128dp<1, 64><<<dim3(64, 32), 256, 0, stream>>>(
        x1b, w1t, b1, nullptr, nullptr, hb, Dm, FFm);
    gemm128dp<2, 64><<<dim3(64, 8), 256, 0, stream>>>(
        hb, w2t, b2, x1b, y2, nullptr, FFm, Dm);
    ln_kernel<0><<<Mm, 256, 0, stream>>>(y2, g2, be2, out, nullptr);
}

// Round 19
// 215.816 us; speedup vs baseline: 1.0188x; 1.0188x over previous
//
#include <hip/hip_runtime.h>
#include <math.h>

// Problem constants
constexpr int Dm  = 1024;
constexpr int Hh  = 16;
constexpr int HDm = 64;
constexpr int FFm = 4096;
constexpr int Bb  = 2;
constexpr int Sq  = 2048;
constexpr int Mm  = Bb * Sq;   // 4096 rows

typedef __attribute__((ext_vector_type(8))) short short8;
typedef __attribute__((ext_vector_type(4))) short short4v;
typedef __attribute__((ext_vector_type(4))) float f32x4;

#define AS1 __attribute__((address_space(1)))
#define AS3 __attribute__((address_space(3)))

// log2(e)/64 : folded into Q so scores come out of QK^T ready for exp2
constexpr float QSCALE = 0.022542110013890054f;

__device__ __forceinline__ unsigned short f2b(float f) {
    union { float f; unsigned u; } v; v.f = f;
    unsigned r = v.u + 0x7FFFu + ((v.u >> 16) & 1u);   // RNE
    return (unsigned short)(r >> 16);
}
__device__ __forceinline__ float b2f(unsigned short s) {
    union { unsigned u; float f; } v; v.u = ((unsigned)s) << 16;
    return v.f;
}

// tanh-form GELU in exp2 domain: x * sigmoid(x*(c1 + c2*x^2)), overflow-safe.
__device__ __forceinline__ float gelu_fast(float x) {
    float z = x * (2.302080918f + 0.102938049f * x * x);
    return x * __builtin_amdgcn_rcpf(1.0f + exp2f(-z));
}

// ---------------------------------------------------------------------------
// Fused prep kernel: one launch does everything.
// ---------------------------------------------------------------------------
__device__ __forceinline__ void transpose_body(
    const float* __restrict__ src, short* __restrict__ dst,
    int R, int C, int bx, int by, int tid, float (*t)[65])
{
    const int c0 = bx * 64, r0 = by * 64;
    const int lc = tid & 63, lr4 = tid >> 6;
    #pragma unroll
    for (int p = 0; p < 16; ++p) {
        int rr = p * 4 + lr4;
        t[rr][lc] = src[(size_t)(r0 + rr) * C + c0 + lc];
    }
    __syncthreads();
    #pragma unroll
    for (int p = 0; p < 16; ++p) {
        int rr = p * 4 + lr4;
        dst[(size_t)(c0 + rr) * R + r0 + lc] = (short)f2b(t[lc][rr]);
    }
}

__global__ __launch_bounds__(256) void prep_all(
    const float* __restrict__ x,  short* __restrict__ xb,
    const float* __restrict__ Wq, const float* __restrict__ Wk,
    const float* __restrict__ Wv, short* __restrict__ wqkvt,
    const float* __restrict__ bq, const float* __restrict__ bk,
    const float* __restrict__ bv, float* __restrict__ bcat,
    const float* __restrict__ Wo, short* __restrict__ wot,
    const float* __restrict__ W1, short* __restrict__ w1t,
    const float* __restrict__ W2, short* __restrict__ w2t)
{
    __shared__ float t[64][65];
    const int bid = blockIdx.x, tid = threadIdx.x;
    if (bid < 256) {
        transpose_body(Wo, wot, Dm, Dm, bid & 15, bid >> 4, tid, t);
    } else if (bid < 1280) {
        int lo = bid - 256;
        transpose_body(W1, w1t, Dm, FFm, lo & 63, lo >> 6, tid, t);
    } else if (bid < 2304) {
        int lo = bid - 1280;
        transpose_body(W2, w2t, FFm, Dm, lo & 15, lo >> 4, tid, t);
    } else if (bid < 2316) {
        int n = (bid - 2304) * 256 + tid;
        const float* s = (n < 1024) ? bq : (n < 2048) ? bk : bv;
        bcat[n] = s[n & 1023];
    } else if (bid < 3084) {
        int lo = bid - 2316;
        const int kt = lo & 15, h = (lo >> 4) & 15, which = lo >> 8;
        const float* W = ((which == 0) ? Wq : (which == 1) ? Wk : Wv) +
                         (size_t)h * Dm * HDm;
        const int lc = tid & 63, lr4 = tid >> 6;
        #pragma unroll
        for (int p = 0; p < 16; ++p) {
            int kr = p * 4 + lr4;
            t[kr][lc] = W[(size_t)(kt * 64 + kr) * HDm + lc];
        }
        __syncthreads();
        const int nbase = which * 1024 + h * 64;
        #pragma unroll
        for (int p = 0; p < 16; ++p) {
            int e = p * 4 + lr4;
            wqkvt[(size_t)(nbase + e) * Dm + kt * 64 + lc] = (short)f2b(t[lc][e]);
        }
    } else {
        int i = (bid - 3084) * 256 + tid;            // float4 index
        float4 v = ((const float4*)x)[i];
        short4v o;
        o[0] = (short)f2b(v.x); o[1] = (short)f2b(v.y);
        o[2] = (short)f2b(v.z); o[3] = (short)f2b(v.w);
        ((short4v*)xb)[i] = o;
    }
}

// ---------------------------------------------------------------------------
// 8-phase 256x256 MFMA GEMM (T2+T3+T4+T5), 512 thr = 8 waves (2M x 4N),
// BK=64, 128 KiB LDS dbuf, counted vmcnt, swapped mfma(bf,af), T1 remap.
// EPI 1: outb = bf16(gelu(acc+bias))  (FF1)
// EPI 2: qkv scatter; q pre-scaled; V written TRANSPOSED [B,H,64,S]
// ---------------------------------------------------------------------------
template<int EPI>
__global__ __launch_bounds__(512, 2) void gemm256(
    const short* __restrict__ A, const short* __restrict__ Bt,
    const float* __restrict__ bias,
    short* __restrict__ outb,
    short* __restrict__ qo, short* __restrict__ ko, short* __restrict__ vo,
    int K, int N, int NMT)
{
    __shared__ __align__(16) char lds[131072];
    char* const ldsA = lds;              // [buf][half] 16KB each
    char* const ldsB = lds + 65536;
    const int tid = threadIdx.x;
    const int l = tid & 63, wv = tid >> 6;
    const int wm = wv >> 2, wn = wv & 3;
    const int lr = l & 15, lg = l >> 4;
    const int cpx = gridDim.x >> 3;
    const int bid = (blockIdx.x & 7) * cpx + (blockIdx.x >> 3);
    const int m0 = (bid % NMT) * 256;
    const int n0 = (bid / NMT) * 256;
    const size_t KB = (size_t)K * 2;
    const int NT = K >> 6;

    const char* pA[2][2];
    const char* pB[2][2];
    #pragma unroll
    for (int i = 0; i < 2; ++i) {
        int c = tid + 512 * i;
        int rh = c >> 3, j = c & 7;
        int sw = (j ^ (rh & 7)) << 4;
        #pragma unroll
        for (int h = 0; h < 2; ++h) {
            pA[h][i] = (const char*)A + (size_t)(m0 + h * 128 + rh) * KB + sw;
            pB[h][i] = (const char*)Bt + (size_t)(n0 + h * 128 + rh) * KB + sw;
        }
    }
    const int dbase = tid * 16;

    f32x4 acc[8][4];
    f32x4 z4 = {0.f, 0.f, 0.f, 0.f};
    #pragma unroll
    for (int i = 0; i < 8; ++i)
        #pragma unroll
        for (int j = 0; j < 4; ++j) acc[i][j] = z4;

#define STAGE_B(h, nb) do {                                                     \
    char* _b = ldsB + ((nb) * 2 + (h)) * 16384;                                 \
    __builtin_amdgcn_global_load_lds((const AS1 void*)pB[h][0],                 \
        (AS3 void*)(_b + dbase), 16, 0, 0);                                     \
    __builtin_amdgcn_global_load_lds((const AS1 void*)pB[h][1],                 \
        (AS3 void*)(_b + dbase + 8192), 16, 0, 0);                              \
    pB[h][0] += 128; pB[h][1] += 128; } while (0)
#define STAGE_A(h, nb) do {                                                     \
    char* _a = ldsA + ((nb) * 2 + (h)) * 16384;                                 \
    __builtin_amdgcn_global_load_lds((const AS1 void*)pA[h][0],                 \
        (AS3 void*)(_a + dbase), 16, 0, 0);                                     \
    __builtin_amdgcn_global_load_lds((const AS1 void*)pA[h][1],                 \
        (AS3 void*)(_a + dbase + 8192), 16, 0, 0);                              \
    pA[h][0] += 128; pA[h][1] += 128; } while (0)

    STAGE_B(0, 0); STAGE_B(1, 0); STAGE_A(0, 0); STAGE_A(1, 0);
    asm volatile("s_waitcnt vmcnt(2)" ::: "memory");
    __builtin_amdgcn_s_barrier();
    __builtin_amdgcn_sched_barrier(0);

    const int swk0 = ((0 + lg) ^ (lr & 7)) << 4;
    const int swk1 = ((4 + lg) ^ (lr & 7)) << 4;

    for (int kt = 0; kt < NT; ++kt) {
        const int buf = kt & 1, nbuf = buf ^ 1;
        const bool more = (kt + 1 < NT);
        char* const Ah0 = ldsA + (buf * 2) * 16384;
        char* const Ah1 = ldsA + (buf * 2 + 1) * 16384;
        char* const Bh  = ldsB + (buf * 2 + (wn >> 1)) * 16384 + (wn & 1) * 8192;

        short8 bf[4][2];
        #pragma unroll
        for (int nf = 0; nf < 4; ++nf) {
            const char* bb = Bh + (nf * 16 + lr) * 128;
            bf[nf][0] = *(const short8*)(bb + swk0);
            bf[nf][1] = *(const short8*)(bb + swk1);
        }
        short8 af[2][2];

#define LOAD_A(p) do {                                                          \
    _Pragma("unroll")                                                           \
    for (int j2 = 0; j2 < 2; ++j2) {                                            \
        const int mf = 2 * (p) + j2;                                            \
        const char* ab = ((mf >> 2) ? Ah1 : Ah0) +                              \
                         ((mf & 3) * 32 + wm * 16 + lr) * 128;                  \
        af[j2][0] = *(const short8*)(ab + swk0);                                \
        af[j2][1] = *(const short8*)(ab + swk1);                                \
    } } while (0)

#define MFMA8(p) do {                                                           \
    _Pragma("unroll")                                                           \
    for (int j2 = 0; j2 < 2; ++j2)                                              \
        _Pragma("unroll")                                                       \
        for (int nf = 0; nf < 4; ++nf) {                                        \
            acc[2 * (p) + j2][nf] = __builtin_amdgcn_mfma_f32_16x16x32_bf16(    \
                bf[nf][0], af[j2][0], acc[2 * (p) + j2][nf], 0, 0, 0);          \
            acc[2 * (p) + j2][nf] = __builtin_amdgcn_mfma_f32_16x16x32_bf16(    \
                bf[nf][1], af[j2][1], acc[2 * (p) + j2][nf], 0, 0, 0);          \
        } } while (0)

        // ---- phase 0 ----
        LOAD_A(0);
        if (more) STAGE_B(0, nbuf);
        __builtin_amdgcn_s_barrier();
        asm volatile("s_waitcnt lgkmcnt(0)" ::: "memory");
        __builtin_amdgcn_sched_barrier(0);
        __builtin_amdgcn_s_setprio(1);
        MFMA8(0);
        __builtin_amdgcn_s_setprio(0);
        __builtin_amdgcn_s_barrier();
        // ---- phase 1 ----
        LOAD_A(1);
        if (more) STAGE_B(1, nbuf);
        __builtin_amdgcn_s_barrier();
        asm volatile("s_waitcnt lgkmcnt(0)" ::: "memory");
        __builtin_amdgcn_sched_barrier(0);
        __builtin_amdgcn_s_setprio(1);
        MFMA8(1);
        __builtin_amdgcn_s_setprio(0);
        if (more) asm volatile("s_waitcnt vmcnt(4)" ::: "memory");
        else      asm volatile("s_waitcnt vmcnt(0)" ::: "memory");
        __builtin_amdgcn_s_barrier();
        __builtin_amdgcn_sched_barrier(0);
        // ---- phase 2 ----
        LOAD_A(2);
        if (more) STAGE_A(0, nbuf);
        __builtin_amdgcn_s_barrier();
        asm volatile("s_waitcnt lgkmcnt(0)" ::: "memory");
        __builtin_amdgcn_sched_barrier(0);
        __builtin_amdgcn_s_setprio(1);
        MFMA8(2);
        __builtin_amdgcn_s_setprio(0);
        __builtin_amdgcn_s_barrier();
        // ---- phase 3 ----
        LOAD_A(3);
        if (more) STAGE_A(1, nbuf);
        __builtin_amdgcn_s_barrier();
        asm volatile("s_waitcnt lgkmcnt(0)" ::: "memory");
        __builtin_amdgcn_sched_barrier(0);
        __builtin_amdgcn_s_setprio(1);
        MFMA8(3);
        __builtin_amdgcn_s_setprio(0);
        asm volatile("s_waitcnt vmcnt(2)" ::: "memory");
        __builtin_amdgcn_s_barrier();
        __builtin_amdgcn_sched_barrier(0);
#undef LOAD_A
#undef MFMA8
    }

    // epilogue (swapped C layout): per (mf,nf): m = ..+lr, n = nb + r
    #pragma unroll
    for (int mf = 0; mf < 8; ++mf) {
        #pragma unroll
        for (int nf = 0; nf < 4; ++nf) {
            const int m  = m0 + mf * 32 + wm * 16 + lr;
            const int nb = n0 + wn * 64 + nf * 16 + lg * 4;
            const float4 b4 = *(const float4*)&bias[nb];
            float v0 = acc[mf][nf][0] + b4.x;
            float v1 = acc[mf][nf][1] + b4.y;
            float v2 = acc[mf][nf][2] + b4.z;
            float v3 = acc[mf][nf][3] + b4.w;
            if (EPI == 1) {
                short4v pk;
                pk[0] = (short)f2b(gelu_fast(v0));
                pk[1] = (short)f2b(gelu_fast(v1));
                pk[2] = (short)f2b(gelu_fast(v2));
                pk[3] = (short)f2b(gelu_fast(v3));
                *(short4v*)&outb[(size_t)m * N + nb] = pk;
            } else {
                const int which = nb >> 10, hh = (nb >> 6) & 15, e0 = nb & 63;
                const int bb2 = m >> 11, ss = m & 2047;
                if (which == 2) {
                    size_t base = (((size_t)bb2 * Hh + hh) * HDm + e0) * Sq + ss;
                    vo[base]          = (short)f2b(v0);
                    vo[base + Sq]     = (short)f2b(v1);
                    vo[base + 2 * Sq] = (short)f2b(v2);
                    vo[base + 3 * Sq] = (short)f2b(v3);
                } else {
                    short* o = (which == 0) ? qo : ko;
                    const float sc = (which == 0) ? QSCALE : 1.0f;
                    short4v pk;
                    pk[0] = (short)f2b(v0 * sc);
                    pk[1] = (short)f2b(v1 * sc);
                    pk[2] = (short)f2b(v2 * sc);
                    pk[3] = (short)f2b(v3 * sc);
                    *(short4v*)&o[(((size_t)bb2 * Hh + hh) * Sq + ss) * HDm + e0] = pk;
                }
            }
        }
    }
#undef STAGE_A
#undef STAGE_B
}

// ---------------------------------------------------------------------------
// Deep-pipelined BMx128 GEMM (T3+T4), 2-phase, swapped mfma, R16 ledger.
// EPI 2: outf = acc + bias + res_bf16 (f32)   (Wo, FF2)
// ---------------------------------------------------------------------------
template<int EPI, int BM>
__global__ __launch_bounds__(256, 2) void gemm128dp(
    const short* __restrict__ A, const short* __restrict__ Bt,
    const float* __restrict__ bias,
    const short* __restrict__ resb,
    float* __restrict__ outf,
    int K, int N)
{
    constexpr int AR  = BM / 32;
    constexpr int BMW = BM / 2;
    constexpr int MF  = BMW / 16;
    constexpr int ABUF = BM * 128;
    __shared__ __align__(16) char lds[2 * ABUF + 32768];
    char* const ldsA = lds;
    char* const ldsB = lds + 2 * ABUF;
    const int tid = threadIdx.x;
    const int l = tid & 63, wv = tid >> 6;
    const int wr = wv >> 1, wc = wv & 1;
    const int lr = l & 15, lg = l >> 4;
    const int m0 = blockIdx.x * BM, n0 = blockIdx.y * 128;
    const size_t KB = (size_t)K * 2;
    const int NT = K >> 6;

    const int r0 = tid >> 3, jj = tid & 7;
    const int sw = (jj ^ (r0 & 7)) << 4;
    const char* aSrc[AR]; const char* bSrc1[2]; const char* bSrc2[2];
    #pragma unroll
    for (int i = 0; i < AR; ++i)
        aSrc[i] = (const char*)A + (size_t)(m0 + r0 + 32 * i) * KB + sw;
    #pragma unroll
    for (int i = 0; i < 2; ++i) {
        bSrc1[i] = (const char*)Bt + (size_t)(n0 + r0 + 64 * i) * KB + sw;
        bSrc2[i] = (const char*)Bt + (size_t)(n0 + 32 + r0 + 64 * i) * KB + sw;
    }
    const int aDst0 = tid * 16;

#define STAGE_SA(nb) do {                                                       \
    char* _a = ldsA + (nb) * ABUF;                                              \
    _Pragma("unroll")                                                           \
    for (int i = 0; i < AR; ++i) {                                              \
        __builtin_amdgcn_global_load_lds((const AS1 void*)aSrc[i],              \
            (AS3 void*)(_a + aDst0 + i * 4096), 16, 0, 0);                      \
        aSrc[i] += 128;                                                         \
    } } while (0)
#define STAGE_SB1(nb) do {                                                      \
    char* _b = ldsB + (nb) * 16384;                                             \
    _Pragma("unroll")                                                           \
    for (int i = 0; i < 2; ++i) {                                               \
        __builtin_amdgcn_global_load_lds((const AS1 void*)bSrc1[i],             \
            (AS3 void*)(_b + aDst0 + i * 8192), 16, 0, 0);                      \
        bSrc1[i] += 128;                                                        \
    } } while (0)
#define STAGE_SB2(nb) do {                                                      \
    char* _b = ldsB + (nb) * 16384 + 4096;                                      \
    _Pragma("unroll")                                                           \
    for (int i = 0; i < 2; ++i) {                                               \
        __builtin_amdgcn_global_load_lds((const AS1 void*)bSrc2[i],             \
            (AS3 void*)(_b + aDst0 + i * 8192), 16, 0, 0);                      \
        bSrc2[i] += 128;                                                        \
    } } while (0)

    f32x4 acc[MF][4];
    f32x4 z4 = {0.f, 0.f, 0.f, 0.f};
    #pragma unroll
    for (int i = 0; i < MF; ++i)
        #pragma unroll
        for (int j = 0; j < 4; ++j) acc[i][j] = z4;

    STAGE_SA(0); STAGE_SB1(0); STAGE_SB2(0);
    asm volatile("s_waitcnt vmcnt(2)" ::: "memory");
    __builtin_amdgcn_s_barrier();
    __builtin_amdgcn_sched_barrier(0);

    for (int kt = 0; kt < NT; ++kt) {
        const int buf = kt & 1, nbuf = buf ^ 1;
        const bool more = (kt + 1 < NT);
        char* const Ab = ldsA + buf * ABUF;
        char* const Bb = ldsB + buf * 16384;

        // ---- phase 1: nf {0,1}; stage ALL of tile t+1 ----
        short8 af[MF][2], bf[2][2];
        #pragma unroll
        for (int mf = 0; mf < MF; ++mf) {
            const int row = wr * BMW + mf * 16 + lr;
            const char* ab = Ab + row * 128;
            af[mf][0] = *(const short8*)(ab + (((0 + lg) ^ (row & 7)) << 4));
            af[mf][1] = *(const short8*)(ab + (((4 + lg) ^ (row & 7)) << 4));
        }
        #pragma unroll
        for (int nf = 0; nf < 2; ++nf) {
            const int row = wc * 64 + nf * 16 + lr;
            const char* bb = Bb + row * 128;
            bf[nf][0] = *(const short8*)(bb + (((0 + lg) ^ (row & 7)) << 4));
            bf[nf][1] = *(const short8*)(bb + (((4 + lg) ^ (row & 7)) << 4));
        }
        if (more) { STAGE_SA(nbuf); STAGE_SB1(nbuf); STAGE_SB2(nbuf); }
        asm volatile("s_waitcnt lgkmcnt(0)" ::: "memory");
        __builtin_amdgcn_sched_barrier(0);
        __builtin_amdgcn_s_setprio(1);
        #pragma unroll
        for (int mf = 0; mf < MF; ++mf)
            #pragma unroll
            for (int nf = 0; nf < 2; ++nf) {
                acc[mf][nf] = __builtin_amdgcn_mfma_f32_16x16x32_bf16(
                    bf[nf][0], af[mf][0], acc[mf][nf], 0, 0, 0);
                acc[mf][nf] = __builtin_amdgcn_mfma_f32_16x16x32_bf16(
                    bf[nf][1], af[mf][1], acc[mf][nf], 0, 0, 0);
            }
        __builtin_amdgcn_s_setprio(0);
        if (more) asm volatile("s_waitcnt vmcnt(6)" ::: "memory");   // forces SB2(t)
        else      asm volatile("s_waitcnt vmcnt(0)" ::: "memory");
        __builtin_amdgcn_s_barrier();
        __builtin_amdgcn_sched_barrier(0);

        // ---- phase 2: nf {2,3} ----
        #pragma unroll
        for (int nf = 0; nf < 2; ++nf) {
            const int row = wc * 64 + (nf + 2) * 16 + lr;
            const char* bb = Bb + row * 128;
            bf[nf][0] = *(const short8*)(bb + (((0 + lg) ^ (row & 7)) << 4));
            bf[nf][1] = *(const short8*)(bb + (((4 + lg) ^ (row & 7)) << 4));
        }
        asm volatile("s_waitcnt lgkmcnt(0)" ::: "memory");
        __builtin_amdgcn_sched_barrier(0);
        __builtin_amdgcn_s_setprio(1);
        #pragma unroll
        for (int mf = 0; mf < MF; ++mf)
            #pragma unroll
            for (int nf = 0; nf < 2; ++nf) {
                acc[mf][nf + 2] = __builtin_amdgcn_mfma_f32_16x16x32_bf16(
                    bf[nf][0], af[mf][0], acc[mf][nf + 2], 0, 0, 0);
                acc[mf][nf + 2] = __builtin_amdgcn_mfma_f32_16x16x32_bf16(
                    bf[nf][1], af[mf][1], acc[mf][nf + 2], 0, 0, 0);
            }
        __builtin_amdgcn_s_setprio(0);
        if (more) {
            asm volatile("s_waitcnt vmcnt(2)" ::: "memory");   // forces SA,SB1(t+1)
            __builtin_amdgcn_s_barrier();
            __builtin_amdgcn_sched_barrier(0);
        }
    }

    // epilogue (swapped C layout)
    #pragma unroll
    for (int mf = 0; mf < MF; ++mf) {
        #pragma unroll
        for (int nf = 0; nf < 4; ++nf) {
            const int m  = m0 + wr * BMW + mf * 16 + lr;
            const int nb = n0 + wc * 64 + nf * 16 + lg * 4;
            const float4 b4 = *(const float4*)&bias[nb];
            float4 o4;
            o4.x = acc[mf][nf][0] + b4.x;
            o4.y = acc[mf][nf][1] + b4.y;
            o4.z = acc[mf][nf][2] + b4.z;
            o4.w = acc[mf][nf][3] + b4.w;
            const short4v r4 = *(const short4v*)&resb[(size_t)m * N + nb];
            o4.x += b2f((unsigned short)r4[0]);
            o4.y += b2f((unsigned short)r4[1]);
            o4.z += b2f((unsigned short)r4[2]);
            o4.w += b2f((unsigned short)r4[3]);
            *(float4*)&outf[(size_t)m * N + nb] = o4;
        }
    }
#undef STAGE_SA
#undef STAGE_SB1
#undef STAGE_SB2
}

// ---------------------------------------------------------------------------
// MFMA flash attention v10 (R15/R17): QBLK=64, 4 waves, KVBLK=128.
// ---------------------------------------------------------------------------
__global__ __launch_bounds__(256) void attn_mfma(
    const short* __restrict__ qg, const short* __restrict__ kg,
    const short* __restrict__ vtg, short* __restrict__ ctx)
{
    const int bid = blockIdx.x;
    const int qt = (Sq / 64 - 1) - (bid >> 5);    // heavy blocks first
    const int hb = bid & 31;
    const int h = hb & 15, b = hb >> 4;
    const int tid = threadIdx.x;
    const int l = tid & 63, wv = tid >> 6;
    const int lr = l & 15, lg = l >> 4;

    __shared__ __align__(16) char KlB[16384];     // 128 key-rows x 128B, swz
    __shared__ __align__(16) char VtB[16384];     // 64 d-rows x 256B, swz
    __shared__ __align__(16) char PlB[4][4096];   // per wave 16 rows x 256B, swz

    const size_t bh = ((size_t)b * Hh + h) * Sq;
    const size_t vbase = ((size_t)b * Hh + h) * HDm * Sq;

    const int qbase = qt * 64 + wv * 16;
    short8 aq[2];
    #pragma unroll
    for (int ks = 0; ks < 2; ++ks)
        aq[ks] = *(const short8*)(qg + (bh + qbase + lr) * HDm + ks * 32 + lg * 8);

    f32x4 zero4 = {0.f, 0.f, 0.f, 0.f};
    f32x4 oacc[4], lacc = zero4;
    #pragma unroll
    for (int i = 0; i < 4; ++i) oacc[i] = zero4;
    float mreg[4];
    #pragma unroll
    for (int r = 0; r < 4; ++r) mreg[r] = -3e38f;

    short8 vone;
    #pragma unroll
    for (int j = 0; j < 8; ++j) vone[j] = (short)0x3F80;   // bf16 1.0

    char* plw = PlB[wv];

    const char* srcK[4]; const char* srcV[4];
    #pragma unroll
    for (int i = 0; i < 4; ++i) {
        int c = tid + 256 * i;
        int rowK = c >> 3, jK = c & 7;              // K: 128 rows x 8 chunks
        srcK[i] = (const char*)kg + ((bh + rowK) * HDm + ((jK ^ (rowK & 7)) * 8)) * 2;
        int rowV = c >> 4, jV = c & 15;             // Vt: 64 rows x 16 chunks
        srcV[i] = (const char*)vtg + (vbase + (size_t)rowV * Sq + ((jV ^ (rowV & 7)) * 8)) * 2;
    }

    const int nt = (qt + 2) >> 1;                   // ceil((qt+1)/2)
    for (int tk = 0; tk < nt; ++tk) {
        __syncthreads();
        #pragma unroll
        for (int i = 0; i < 4; ++i) {
            int c = tid + 256 * i;
            __builtin_amdgcn_global_load_lds((const AS1 void*)srcK[i],
                (AS3 void*)(KlB + c * 16), 16, 0, 0);
            srcK[i] += 128 * HDm * 2;               // next 128-key tile
            __builtin_amdgcn_global_load_lds((const AS1 void*)srcV[i],
                (AS3 void*)(VtB + c * 16), 16, 0, 0);
            srcV[i] += 128 * 2;                     // 128 keys along S
        }
        __syncthreads();

        // QK^T: S[16 q][128 key]
        f32x4 sc[8];
        #pragma unroll
        for (int i = 0; i < 8; ++i) sc[i] = zero4;
        __builtin_amdgcn_s_setprio(1);
        #pragma unroll
        for (int kd = 0; kd < 2; ++kd) {
            #pragma unroll
            for (int nf = 0; nf < 8; ++nf) {
                short8 bk = *(const short8*)(KlB + (nf * 16 + lr) * 128 +
                                (((kd * 4 + lg) ^ (lr & 7)) << 4));
                sc[nf] = __builtin_amdgcn_mfma_f32_16x16x32_bf16(
                    aq[kd], bk, sc[nf], 0, 0, 0);
            }
        }
        __builtin_amdgcn_s_setprio(0);

        // mask (last tile only)
        if (tk == nt - 1) {
            #pragma unroll
            for (int r = 0; r < 4; ++r) {
                const int qglob = qbase + lg * 4 + r;
                #pragma unroll
                for (int nf = 0; nf < 8; ++nf)
                    if (tk * 128 + nf * 16 + lr > qglob) sc[nf][r] = -3e38f;
            }
        }

        // fast-path softmax: per-lane max (serial chain -> v_max3 fusion)
        float lm[4];
        #pragma unroll
        for (int r = 0; r < 4; ++r) {
            float m01 = fmaxf(fmaxf(fmaxf(sc[0][r], sc[1][r]), sc[2][r]), sc[3][r]);
            lm[r] = fmaxf(fmaxf(fmaxf(fmaxf(m01, sc[4][r]), sc[5][r]), sc[6][r]), sc[7][r]);
        }
        bool grow = (lm[0] > mreg[0] + 8.f) || (lm[1] > mreg[1] + 8.f) ||
                    (lm[2] > mreg[2] + 8.f) || (lm[3] > mreg[3] + 8.f);

        if (__any((int)grow)) {
            #pragma unroll
            for (int r = 0; r < 4; ++r) {
                float mr = lm[r];
                #pragma unroll
                for (int o = 1; o < 16; o <<= 1)
                    mr = fmaxf(mr, __shfl_xor(mr, o));
                float mnew = fmaxf(mreg[r], mr);
                float cf = exp2f(mreg[r] - mnew);
                mreg[r] = mnew;
                const int prow = lg * 4 + r;
                #pragma unroll
                for (int nf = 0; nf < 8; ++nf) {
                    float p = exp2f(sc[nf][r] - mnew);
                    *(unsigned short*)(plw + prow * 256 +
                        (((nf * 2 + (lr >> 3)) ^ (prow & 7)) << 4) +
                        ((lr & 7) << 1)) = (unsigned short)(__float_as_uint(p) >> 16);
                }
                #pragma unroll
                for (int nf = 0; nf < 4; ++nf) oacc[nf][r] *= cf;
                lacc[r] *= cf;
            }
        } else {
            #pragma unroll
            for (int r = 0; r < 4; ++r) {
                const int prow = lg * 4 + r;
                #pragma unroll
                for (int nf = 0; nf < 8; ++nf) {
                    float p = exp2f(sc[nf][r] - mreg[r]);
                    *(unsigned short*)(plw + prow * 256 +
                        (((nf * 2 + (lr >> 3)) ^ (prow & 7)) << 4) +
                        ((lr & 7) << 1)) = (unsigned short)(__float_as_uint(p) >> 16);
                }
            }
        }

        asm volatile("s_waitcnt lgkmcnt(0)" ::: "memory");
        __builtin_amdgcn_sched_barrier(0);

        // PV: O[16 q][64 d] += P @ V over 128 keys ; l via ones-MFMA
        __builtin_amdgcn_s_setprio(1);
        #pragma unroll
        for (int ks = 0; ks < 4; ++ks) {
            short8 pa = *(const short8*)(plw + lr * 256 +
                            (((ks * 4 + lg) ^ (lr & 7)) << 4));
            #pragma unroll
            for (int nf = 0; nf < 4; ++nf) {
                short8 bv8 = *(const short8*)(VtB + (nf * 16 + lr) * 256 +
                                (((ks * 4 + lg) ^ (lr & 7)) << 4));
                oacc[nf] = __builtin_amdgcn_mfma_f32_16x16x32_bf16(
                    pa, bv8, oacc[nf], 0, 0, 0);
            }
            lacc = __builtin_amdgcn_mfma_f32_16x16x32_bf16(pa, vone, lacc, 0, 0, 0);
        }
        __builtin_amdgcn_s_setprio(0);
    }

    #pragma unroll
    for (int r = 0; r < 4; ++r) {
        float inv = 1.0f / lacc[r];
        int q = qbase + lg * 4 + r;
        size_t o = ((size_t)b * Sq + q) * Dm + h * HDm;
        #pragma unroll
        for (int nf = 0; nf < 4; ++nf)
            ctx[o + nf * 16 + lr] = (short)f2b(oacc[nf][r] * inv);
    }
}

// ---------------------------------------------------------------------------
// Row LayerNorm: block per row (1024), 256 thr x float4.
// MODE 0: f32 out (final). MODE 1: bf16 out only (feeds FF1 + FF2 residual).
// ---------------------------------------------------------------------------
template<int MODE>
__global__ __launch_bounds__(256) void ln_kernel(
    const float* __restrict__ in, const float* __restrict__ g,
    const float* __restrict__ be, float* __restrict__ outf,
    short* __restrict__ outb)
{
    const int m = blockIdx.x;
    const int tid = threadIdx.x;
    const float4 vl = *(const float4*)&in[(size_t)m * Dm + tid * 4];
    float s  = vl.x + vl.y + vl.z + vl.w;
    float s2 = vl.x * vl.x + vl.y * vl.y + vl.z * vl.z + vl.w * vl.w;
    #pragma unroll
    for (int o = 32; o > 0; o >>= 1) {
        s  += __shfl_down(s, o);
        s2 += __shfl_down(s2, o);
    }
    __shared__ float rs[4], rs2[4];
    const int w = tid >> 6;
    if ((tid & 63) == 0) { rs[w] = s; rs2[w] = s2; }
    __syncthreads();
    s  = rs[0] + rs[1] + rs[2] + rs[3];
    s2 = rs2[0] + rs2[1] + rs2[2] + rs2[3];
    const float mean = s * (1.0f / Dm);
    const float var  = s2 * (1.0f / Dm) - mean * mean;
    const float rstd = rsqrtf(var + 1e-5f);
    const float4 gv = *(const float4*)&g[tid * 4];
    const float4 bv = *(const float4*)&be[tid * 4];
    float4 ov;
    ov.x = (vl.x - mean) * rstd * gv.x + bv.x;
    ov.y = (vl.y - mean) * rstd * gv.y + bv.y;
    ov.z = (vl.z - mean) * rstd * gv.z + bv.z;
    ov.w = (vl.w - mean) * rstd * gv.w + bv.w;
    if (MODE == 0) {
        *(float4*)&outf[(size_t)m * Dm + tid * 4] = ov;
    } else {
        short4v o4;
        o4[0] = (short)f2b(ov.x); o4[1] = (short)f2b(ov.y);
        o4[2] = (short)f2b(ov.z); o4[3] = (short)f2b(ov.w);
        *(short4v*)&outb[(size_t)m * Dm + tid * 4] = o4;
    }
}

// ---------------------------------------------------------------------------
extern "C" void kernel_launch(void* const* d_in, const int* in_sizes, int n_in,
                              void* d_out, int out_size, void* d_ws, size_t ws_size,
                              hipStream_t stream)
{
    const float* x  = (const float*)d_in[0];
    const float* Wq = (const float*)d_in[1];
    const float* bq = (const float*)d_in[2];
    const float* Wk = (const float*)d_in[3];
    const float* bk = (const float*)d_in[4];
    const float* Wv = (const float*)d_in[5];
    const float* bv = (const float*)d_in[6];
    const float* Wo = (const float*)d_in[7];
    const float* bo = (const float*)d_in[8];
    const float* W1 = (const float*)d_in[9];
    const float* b1 = (const float*)d_in[10];
    const float* W2 = (const float*)d_in[11];
    const float* b2 = (const float*)d_in[12];
    const float* g1 = (const float*)d_in[13];
    const float* be1= (const float*)d_in[14];
    const float* g2 = (const float*)d_in[15];
    const float* be2= (const float*)d_in[16];
    float* out = (float*)d_out;

    char* ws = (char*)d_ws;
    size_t off = 0;
    auto alloc = [&](size_t bytes) {
        char* p = ws + off;
        off += (bytes + 255) & ~(size_t)255;
        return p;
    };
    const size_t MD2 = (size_t)Mm * Dm * 2;          // 8 MB
    short* xb    = (short*)alloc(MD2);
    short* wqkvt = (short*)alloc((size_t)3072 * Dm * 2);
    float* bcat  = (float*)alloc(3072 * 4);
    short* wot   = (short*)alloc((size_t)Dm * Dm * 2);
    short* w1t   = (short*)alloc((size_t)FFm * Dm * 2);
    short* w2t   = (short*)alloc((size_t)Dm * FFm * 2);
    short* qb    = (short*)alloc(MD2);
    short* kb    = (short*)alloc(MD2);
    short* vtb   = (short*)alloc(MD2);               // V transposed [B,H,64,S]
    short* ctxb  = (short*)alloc(MD2);
    short* hb    = qb;                                // alias: q/k dead by FF1
    float* y     = (float*)alloc((size_t)Mm * Dm * 4);
    short* x1b   = (short*)alloc(MD2);
    float* y2    = y;                                 // alias: y dead after LN1

    // --- fused prep (1 launch) ---
    prep_all<<<7180, 256, 0, stream>>>(
        x, xb, Wq, Wk, Wv, wqkvt, bq, bk, bv, bcat,
        Wo, wot, W1, w1t, W2, w2t);

    // --- decoder layer ---
    gemm256<2><<<192, 512, 0, stream>>>(
        xb, wqkvt, bcat, nullptr, qb, kb, vtb, Dm, 3072, 16);
    attn_mfma<<<1024, 256, 0, stream>>>(qb, kb, vtb, ctxb);
    gemm128dp<2, 64><<<dim3(64, 8), 256, 0, stream>>>(
        ctxb, wot, bo, xb, y, Dm, Dm);
    ln_kernel<1><<<Mm, 256, 0, stream>>>(y, g1, be1, nullptr, x1b);
    gemm256<1><<<256, 512, 0, stream>>>(
        x1b, w1t, b1, hb, nullptr, nullptr, nullptr, Dm, FFm, 16);
    gemm128dp<2, 64><<<dim3(64, 8), 256, 0, stream>>>(
        hb, w2t, b2, x1b, y2, FFm, Dm);
    ln_kernel<0><<<Mm, 256, 0, stream>>>(y2, g2, be2, out, nullptr);
}